// Round 1
// baseline (362.986 us; speedup 1.0000x reference)
//
#include <hip/hip_runtime.h>
#include <math.h>

#define NN 512
#define KP 64
#define NPANEL 8

// ---------------------------------------------------------------------------
// Exp-domain soft Floyd-Warshall:
//   E = exp(-w/gamma);  step k:  E += outer(E[:,k], E[k,:])   (rank-1, Jacobi)
// Blocked into 8 panels of K=64: diag-block evolution (serial chain) +
// forward-substitution for panel snapshots + rank-64 GEMM trailing update.
// Exact reassociation of the reference recurrence (all terms >= 0).
// ---------------------------------------------------------------------------

__global__ __launch_bounds__(256) void k_init(const float* __restrict__ s,
                                              const float* __restrict__ d,
                                              float* __restrict__ E) {
  const int idx = blockIdx.x * 256 + threadIdx.x;
  const int i = idx >> 9, j = idx & (NN - 1);
  float w = d[idx] / (s[idx] + 1e-4f);
  if (i == j) w = 0.0f;                 // reference zeroes diagonal of w0
  E[idx] = expf(-10.0f * w);            // exp(-w/gamma), gamma=0.1
}

// One panel: 16 blocks x 256 threads.
// blocks 0..7  : column-panel slices (rows 64b..64b+63), need row-snapshots U=DR
// blocks 8..15 : row-panel slices   (cols 64(b-8)..),    need col-snapshots U=DC
// Every block redundantly evolves the 64x64 diagonal block D in registers,
// publishing row m / col m through LDS each sub-step (1 barrier per sub-step).
__global__ __launch_bounds__(256) void k_panel(const float* __restrict__ E,
                                               float* __restrict__ Csnap,
                                               float* __restrict__ Rsnap,
                                               int k0) {
  __shared__ float rowb[2][KP];   // published D[m][*] (double-buffered)
  __shared__ float colb[2][KP];   // published D[*][m]
  __shared__ float U[KP][KP];     // snapshot history this block needs
  const int tid = threadIdx.x;
  const int b = blockIdx.x;
  const bool isC = (b < 8);
  const int t = tid & 63;         // column of D owned by this thread
  const int c = tid >> 6;         // 0..3 ; thread owns rows a = c + 4*i

  // D register tile: dreg[i] = D[c + 4*i][t]
  float dreg[16];
#pragma unroll
  for (int i = 0; i < 16; ++i)
    dreg[i] = E[(size_t)(k0 + c + 4 * i) * NN + (k0 + t)];

#pragma unroll
  for (int m = 0; m < KP; ++m) {
    const int q = m & 1;
    // publish row m (owners: c == m&3, register index m>>2 — static via unroll)
    if (c == (m & 3)) rowb[q][t] = dreg[m >> 2];
    // publish col m (owners: t == m; their 16 regs are D[c+4i][m])
    if (t == m) {
#pragma unroll
      for (int i = 0; i < 16; ++i) colb[q][c + 4 * i] = dreg[i];
    }
    __syncthreads();
    // record the snapshot row this block's substitution will need
    if (tid < KP) U[m][tid] = isC ? rowb[q][tid] : colb[q][tid];
    // rank-1 update of owned D entries (Jacobi: uses pre-step row/col)
    const float rm = rowb[q][t];
#pragma unroll
    for (int i = 0; i < 16; ++i) dreg[i] += colb[q][c + 4 * i] * rm;
  }
  __syncthreads();

  // Forward substitution: snapshot panels from initial slices + U history.
  //   Csnap[i][m] = C0[i][m] + sum_{m'<m} Csnap[i][m'] * U[m'][m]
  // (identical form for R with U = col-snapshot history)
  if (tid < 64) {
    float v[KP];
    if (isC) {
      const int row = b * 64 + tid;
      const float4* p4 = (const float4*)(E + (size_t)row * NN + k0);
#pragma unroll
      for (int m4 = 0; m4 < 16; ++m4) {
        const float4 x = p4[m4];
        v[4 * m4 + 0] = x.x; v[4 * m4 + 1] = x.y;
        v[4 * m4 + 2] = x.z; v[4 * m4 + 3] = x.w;
      }
#pragma unroll
      for (int mp = 0; mp < KP - 1; ++mp)
#pragma unroll
        for (int m = mp + 1; m < KP; ++m)
          v[m] += v[mp] * U[mp][m];
      float4* o4 = (float4*)(Csnap + (size_t)row * KP);
#pragma unroll
      for (int m4 = 0; m4 < 16; ++m4)
        o4[m4] = make_float4(v[4 * m4], v[4 * m4 + 1], v[4 * m4 + 2], v[4 * m4 + 3]);
    } else {
      const int col = (b - 8) * 64 + tid;
#pragma unroll
      for (int m = 0; m < KP; ++m) v[m] = E[(size_t)(k0 + m) * NN + col];
#pragma unroll
      for (int mp = 0; mp < KP - 1; ++mp)
#pragma unroll
        for (int m = mp + 1; m < KP; ++m)
          v[m] += v[mp] * U[mp][m];
#pragma unroll
      for (int m = 0; m < KP; ++m) Rsnap[(size_t)m * NN + col] = v[m];
    }
  }
}

// Trailing rank-64 update: E += Csnap(NxK) * Rsnap(KxN), fp32.
__global__ __launch_bounds__(256) void k_gemm(float* __restrict__ E,
                                              const float* __restrict__ Csnap,
                                              const float* __restrict__ Rsnap) {
  const int tid = threadIdx.x;
  const int idx0 = blockIdx.x * 1024 + tid * 4;    // 4 elements per thread
  const int i = idx0 >> 9;
  const int j = idx0 & 511;
  const float* crow = Csnap + (size_t)i * KP;
  float4 acc = *(const float4*)(E + idx0);
#pragma unroll 8
  for (int m = 0; m < KP; ++m) {
    const float cs = crow[m];                       // wave-uniform, L1-hit
    const float4 r = *(const float4*)(Rsnap + (size_t)m * NN + j);
    acc.x += cs * r.x; acc.y += cs * r.y;
    acc.z += cs * r.z; acc.w += cs * r.w;
  }
  *(float4*)(E + idx0) = acc;
}

// Final fused loss: per-element terms + block reduce + atomicAdd.
__global__ __launch_bounds__(256) void k_loss(const float* __restrict__ s,
                                              const float* __restrict__ o,
                                              const float* __restrict__ d,
                                              const float* __restrict__ f,
                                              const int* __restrict__ ep,
                                              const float* __restrict__ E,
                                              float* __restrict__ out) {
  const int tid = threadIdx.x;
  const int idx = blockIdx.x * 256 + tid;
  const int i = idx >> 9, j = idx & 511;
  const float sv = s[idx], dv = d[idx], fv = f[idx], ov = o[idx], Ev = E[idx];

  // shortest path back from exp domain; clamp underflow (both sides give +1)
  const float sp = (Ev > 0.0f) ? (-0.1f * logf(Ev)) : 1e9f;
  const float ur = expf(-0.005f * sp);   // exp(UTILITY_SCALE * sp * PRIORITY_RAIL)
  const float ub = expf(-0.01f * dv);    // exp(UTILITY_SCALE * d)
  const float choice = ur / (ur + ub);   // ub >= exp(-1) > 0, no div-by-0
  const float ug = fv * choice * (dv - 0.5f * sp);
  const float util = (ug > 0.0f) ? (ug + 1.0f) : expf(ug);  // elu(x)+1, alpha=1

  const float ent = sv * (((i == j) ? 1.0f : 0.0f) - sv);
  const int e = ep[0];
  // bisect_right([0,10,50], e) -> levels [0, .05, .1, 1.0]
  const float esc = (e < 0) ? 0.0f : (e < 10) ? 0.05f : (e < 50) ? 0.1f : 1.0f;

  float acc = sv * dv + util + esc * ent * ent + 10000.0f * (sv * (1.0f - ov));

  __shared__ float red[256];
  red[tid] = acc;
  __syncthreads();
#pragma unroll
  for (int st = 128; st > 0; st >>= 1) {
    if (tid < st) red[tid] += red[tid + st];
    __syncthreads();
  }
  if (tid == 0) atomicAdd(out, red[0]);
}

extern "C" void kernel_launch(void* const* d_in, const int* in_sizes, int n_in,
                              void* d_out, int out_size, void* d_ws, size_t ws_size,
                              hipStream_t stream) {
  const float* s = (const float*)d_in[0];   // soft_adj
  const float* o = (const float*)d_in[1];   // original_adj
  const float* d = (const float*)d_in[2];   // distances
  const float* f = (const float*)d_in[3];   // flow
  const int* ep = (const int*)d_in[4];      // epoch (1 elem)
  float* out = (float*)d_out;

  float* E = (float*)d_ws;                  // 512*512 floats (1 MB)
  float* Csnap = E + NN * NN;               // 512*64
  float* Rsnap = Csnap + NN * KP;           // 64*512

  hipMemsetAsync(d_out, 0, sizeof(float), stream);
  k_init<<<1024, 256, 0, stream>>>(s, d, E);
  for (int p = 0; p < NPANEL; ++p) {
    k_panel<<<16, 256, 0, stream>>>(E, Csnap, Rsnap, p * KP);
    k_gemm<<<256, 256, 0, stream>>>(E, Csnap, Rsnap);
  }
  k_loss<<<1024, 256, 0, stream>>>(s, o, d, f, ep, E, out);
}